// Round 12
// baseline (77.601 us; speedup 1.0000x reference)
//
#include <hip/hip_runtime.h>

typedef __bf16 bf16;
typedef __attribute__((ext_vector_type(8))) __bf16 bf16x8;
typedef __attribute__((ext_vector_type(4))) __bf16 bf16x4;
typedef __attribute__((ext_vector_type(4))) float f32x4;
typedef __attribute__((ext_vector_type(16))) float f32x16;
typedef __attribute__((ext_vector_type(2))) unsigned u32x2;

#define MFMA(a, b, c) __builtin_amdgcn_mfma_f32_16x16x32_bf16(a, b, c, 0, 0, 0)
#define MFMA32(a, b, c) __builtin_amdgcn_mfma_f32_32x32x16_bf16(a, b, c, 0, 0, 0)
#define GLOAD_LDS(g, l)                                                        \
  __builtin_amdgcn_global_load_lds(                                            \
      (const __attribute__((address_space(1))) void*)(g),                      \
      (__attribute__((address_space(3))) void*)(l), 16, 0, 0)

#if __has_builtin(__builtin_amdgcn_exp2f)
#define EXP2(x) __builtin_amdgcn_exp2f(x)
#else
#define EXP2(x) exp2f(x)
#endif

// 0.125 (qk scale) * log2(e): folded into K at the QKV epilogue.
#define C1LOG 0.18033688011f

// [rows][64] bf16 tile swizzle: XOR 16B-chunk index with (row&7).
__device__ __forceinline__ int swz64(int row, int col) {
  return row * 64 + (col ^ ((row & 7) << 3));
}

// pack two f32 -> u32 of 2 bf16 (lo = a)
__device__ __forceinline__ unsigned pk2(float a, float b) {
  union { __bf16 h[2]; unsigned u; } z;
  z.h[0] = (__bf16)a; z.h[1] = (__bf16)b;
  return z.u;
}

// exchange: a.hi32lanes <-> b.lo32lanes (v_permlane32_swap_b32)
__device__ __forceinline__ void plswap2(unsigned& a, unsigned& b) {
#if __has_builtin(__builtin_amdgcn_permlane32_swap)
  u32x2 r = __builtin_amdgcn_permlane32_swap(a, b, false, false);
  a = r[0]; b = r[1];
#else
  asm volatile("s_nop 1\n\tv_permlane32_swap_b32 %0, %1\n\ts_nop 1"
               : "+v"(a), "+v"(b));
#endif
}

// ----------------- fused GroupNorm + weight conversion -----------------
__global__ __launch_bounds__(256, 2) void k_pre(
    const float* __restrict__ x, const float* __restrict__ gs,
    const float* __restrict__ gb, const float* __restrict__ qw,
    const float* __restrict__ pw, bf16* __restrict__ xnT,
    bf16* __restrict__ wq, bf16* __restrict__ wp) {
  int tid = threadIdx.x;
  if (blockIdx.x >= 256) {
    int i = (blockIdx.x - 256) * 256 + tid;
    int idx = i * 4;
    float4 v;
    bf16* o;
    if (idx < 786432) {
      v = *(const float4*)(qw + idx);
      o = wq + idx;
    } else {
      int j = idx - 786432;
      v = *(const float4*)(pw + j);
      o = wp + j;
    }
    o[0] = (bf16)v.x; o[1] = (bf16)v.y; o[2] = (bf16)v.z; o[3] = (bf16)v.w;
    return;
  }
  __shared__ float xs[16 * 1024];  // [ch][t], 64KB
  __shared__ float red[2][4];
  int blk = blockIdx.x;
  int b = blk >> 5, g = blk & 31;
  const float* xp = x + ((size_t)(b * 512 + g * 16)) * 1024;
  float s = 0.f, ss = 0.f;
  for (int i = tid; i < 4096; i += 256) {
    float4 v = ((const float4*)xp)[i];
    *(float4*)&xs[i * 4] = v;
    s += v.x + v.y + v.z + v.w;
    ss += v.x * v.x + v.y * v.y + v.z * v.z + v.w * v.w;
  }
#pragma unroll
  for (int m = 1; m < 64; m <<= 1) {
    s += __shfl_xor(s, m);
    ss += __shfl_xor(ss, m);
  }
  int wid = tid >> 6;
  if ((tid & 63) == 0) { red[0][wid] = s; red[1][wid] = ss; }
  __syncthreads();
  float fs = red[0][0] + red[0][1] + red[0][2] + red[0][3];
  float fss = red[1][0] + red[1][1] + red[1][2] + red[1][3];
  float mean = fs * (1.f / 16384.f);
  float var = fss * (1.f / 16384.f) - mean * mean;
  float inv = rsqrtf(var + 1e-5f);
  float a_[16], b_[16];
#pragma unroll
  for (int cl = 0; cl < 16; ++cl) {
    float sc = gs[g * 16 + cl] * inv;
    a_[cl] = sc;
    b_[cl] = gb[g * 16 + cl] - mean * sc;
  }
  int t0 = tid * 4;
  bf16 tmp[4][16];
#pragma unroll
  for (int cl = 0; cl < 16; ++cl) {
    float4 v = *(float4*)&xs[cl * 1024 + t0];
    tmp[0][cl] = (bf16)(v.x * a_[cl] + b_[cl]);
    tmp[1][cl] = (bf16)(v.y * a_[cl] + b_[cl]);
    tmp[2][cl] = (bf16)(v.z * a_[cl] + b_[cl]);
    tmp[3][cl] = (bf16)(v.w * a_[cl] + b_[cl]);
  }
  bf16* outp = xnT + (size_t)b * 1024 * 512 + g * 16;
#pragma unroll
  for (int k = 0; k < 4; ++k) {
    *(bf16x8*)(outp + (size_t)(t0 + k) * 512) = *(bf16x8*)&tmp[k][0];
    *(bf16x8*)(outp + (size_t)(t0 + k) * 512 + 8) = *(bf16x8*)&tmp[k][8];
  }
}

// ------------------------------ QKV GEMM -------------------------------
// 128x128 tile, BK=64, global_load_lds + swizzle. Epilogue: bias; K cols
// pre-scaled by 0.125*log2e; V cols written transposed into vT[head][c][s].
__global__ void k_qkv(const bf16* __restrict__ xnT, const bf16* __restrict__ wq,
                      const float* __restrict__ qb, bf16* __restrict__ qkvT,
                      bf16* __restrict__ vTout) {
  int bid = blockIdx.x;
  int swz = (bid & 7) * 96 + (bid >> 3);
  int nt = swz % 12, mt = swz / 12;
  int tid = threadIdx.x, lane = tid & 63;
  int wid = tid >> 6, wr = wid >> 1, wc = wid & 1;
  int lr = lane & 15, lk8 = (lane >> 4) * 8, prow4 = (lane >> 4) * 4;
  __shared__ __align__(16) bf16 lA[8192], lB[8192];
  const bf16* Ab = xnT + (size_t)mt * 128 * 512;
  const bf16* Bb = wq + (size_t)nt * 128 * 512;
  f32x4 acc[4][4] = {};
  int ubase = tid & 192;
  for (int kt = 0; kt < 8; ++kt) {
    __syncthreads();
#pragma unroll
    for (int i = 0; i < 4; ++i) {
      int s = i * 256 + tid;
      int r = s >> 3, cc = (s & 7) ^ (r & 7);
      GLOAD_LDS(Ab + (size_t)r * 512 + kt * 64 + cc * 8, lA + (i * 256 + ubase) * 8);
      GLOAD_LDS(Bb + (size_t)r * 512 + kt * 64 + cc * 8, lB + (i * 256 + ubase) * 8);
    }
    __syncthreads();
#pragma unroll
    for (int ksl = 0; ksl < 2; ++ksl) {
      bf16x8 aF[4], bF[4];
#pragma unroll
      for (int m = 0; m < 4; ++m)
        aF[m] = *(bf16x8*)&lA[swz64(wr * 64 + m * 16 + lr, ksl * 32 + lk8)];
#pragma unroll
      for (int n = 0; n < 4; ++n)
        bF[n] = *(bf16x8*)&lB[swz64(wc * 64 + n * 16 + lr, ksl * 32 + lk8)];
      __builtin_amdgcn_s_setprio(1);
#pragma unroll
      for (int m = 0; m < 4; ++m)
#pragma unroll
        for (int n = 0; n < 4; ++n) acc[m][n] = MFMA(aF[m], bF[n], acc[m][n]);
      __builtin_amdgcn_s_setprio(0);
    }
  }
#pragma unroll
  for (int n = 0; n < 4; ++n) {
    int o = nt * 128 + wc * 64 + n * 16 + lr;
    float bias = qb[o];
    int hh = o / 192;
    int om = o - hh * 192;
    bool isv = om >= 128;
    float scl = (om >= 64 && om < 128) ? C1LOG : 1.0f;
    int c = om - 128;
#pragma unroll
    for (int m = 0; m < 4; ++m) {
      int row0 = mt * 128 + wr * 64 + m * 16 + prow4;
      if (isv) {
        int bb = row0 >> 10, t0 = row0 & 1023;
        bf16x4 v4;
#pragma unroll
        for (int r = 0; r < 4; ++r) v4[r] = (bf16)(acc[m][n][r] + bias);
        *(bf16x4*)&vTout[(((size_t)bb * 8 + hh) * 64 + c) * 1024 + t0] = v4;
      } else {
#pragma unroll
        for (int r = 0; r < 4; ++r)
          qkvT[(size_t)(row0 + r) * 1536 + o] = (bf16)((acc[m][n][r] + bias) * scl);
      }
    }
  }
}

// --------------------------- flash attention ---------------------------
// 32x32-fragment structure (m214-style): 4 waves x 32 q-rows; swapped
// QK^T = MFMA32(K,Q) -> lane owns all P for q=lane&31 (row softmax = tree
// + ONE shfl_xor(32)); P -> PV B-frag entirely in registers via cvt_pk +
// permlane32_swap (no P LDS round-trip); PV = MFMA32(V,P); denominator
// via MFMA32(ones,P). K/V LDS reads per q-row HALVED vs 16x16 version.
__global__ __launch_bounds__(256, 2) void k_attn(const bf16* __restrict__ qkvT,
                                                 const bf16* __restrict__ vT,
                                                 bf16* __restrict__ hT) {
  int d = blockIdx.x;
  int head = (d & 7) * 8 + (d >> 6);  // all 8 q-tiles of a head on one XCD
  int qt = (d >> 3) & 7;
  int b = head >> 3, hh = head & 7;
  int tid = threadIdx.x, lane = tid & 63, wv = tid >> 6;  // wv 0..3
  int l32 = lane & 31, h = lane >> 5;                      // h in {0,1}

  __shared__ __align__(16) bf16 KT[2][4096];   // [s=64][c=64] swz rows
  __shared__ __align__(16) bf16 VTl[2][4096];  // [c=64][s=64] swz rows

  const bf16* qbase = qkvT + (size_t)b * 1024 * 1536 + hh * 192;
  const bf16* kbase = qbase + 64;
  const bf16* vbase = vT + (size_t)head * 64 * 1024;

  int tq = qt * 128 + wv * 32 + l32;  // this lane's q row
  // Q as 32x32x16 B-operand: col=q=l32, k(c) = 16*ks + 8h + j
  bf16x8 qB[4];
#pragma unroll
  for (int ks = 0; ks < 4; ++ks)
    qB[ks] = *(const bf16x8*)(qbase + (size_t)tq * 1536 + ks * 16 + h * 8);

  f32x16 hacc[2] = {};  // h[c][q]: cchunk 0 -> c 0..31, 1 -> c 32..63
  f32x16 lsum = {};
  float m2 = -1e30f;

  // staging: 512 slots of 8 elems per 64x64 tile; 2 K + 2 V slots/thread
  int rr8 = tid >> 3;                        // 0..31
  int cc_ = (tid & 7) ^ (rr8 & 7);
  const bf16* ks_ = kbase + (size_t)rr8 * 1536 + cc_ * 8;
  const bf16* vs_ = vbase + (size_t)rr8 * 1024 + cc_ * 8;
  int ldst = wv * 512;  // wave-uniform element base; + i*2048

  bf16x8 ones;
#pragma unroll
  for (int j = 0; j < 8; ++j) ones[j] = (bf16)1.0f;

  // prologue: tile 0
#pragma unroll
  for (int i = 0; i < 2; ++i) {
    GLOAD_LDS(ks_ + (size_t)i * 32 * 1536, KT[0] + i * 2048 + ldst);
    GLOAD_LDS(vs_ + (size_t)i * 32 * 1024, VTl[0] + i * 2048 + ldst);
  }

  for (int it = 0; it < 16; ++it) {
    int cur = it & 1;
    asm volatile("s_waitcnt vmcnt(0)" ::: "memory");
    __builtin_amdgcn_s_barrier();
    __builtin_amdgcn_sched_barrier(0);
    if (it < 15) {  // prefetch next 64-row tile
      size_t sb = (size_t)(it + 1) * 64;
#pragma unroll
      for (int i = 0; i < 2; ++i) {
        GLOAD_LDS(ks_ + (sb + i * 32) * 1536, KT[cur ^ 1] + i * 2048 + ldst);
        GLOAD_LDS(vs_ + sb + (size_t)i * 32 * 1024,
                  VTl[cur ^ 1] + i * 2048 + ldst);
      }
    }
    // QK^T: sc[w] = S[s=32w + (r&3)+8(r>>2)+4h][q=l32]  (log2 domain)
    f32x16 sc[2] = {};
    __builtin_amdgcn_s_setprio(1);
#pragma unroll
    for (int w = 0; w < 2; ++w)
#pragma unroll
      for (int ks = 0; ks < 4; ++ks) {
        bf16x8 kA = *(bf16x8*)&KT[cur][swz64(32 * w + l32, 16 * ks + 8 * h)];
        sc[w] = MFMA32(kA, qB[ks], sc[w]);
      }
    __builtin_amdgcn_s_setprio(0);
    // row max over 32 regs (all s for q=l32 in this lane + partner h-lane)
    float mx[8];
#pragma unroll
    for (int g = 0; g < 8; ++g) {
      const f32x16& v = sc[g >> 2];
      int r0 = (g & 3) * 4;
      mx[g] = fmaxf(fmaxf(v[r0], v[r0 + 1]), fmaxf(v[r0 + 2], v[r0 + 3]));
    }
    float tm = fmaxf(fmaxf(fmaxf(mx[0], mx[1]), fmaxf(mx[2], mx[3])),
                     fmaxf(fmaxf(mx[4], mx[5]), fmaxf(mx[6], mx[7])));
    tm = fmaxf(tm, __shfl_xor(tm, 32));
    if (__any(tm > m2 + 7.213f)) {  // defer-max (5 nats, log2 domain)
      float mn = fmaxf(m2, tm);
      float al = EXP2(m2 - mn);
      m2 = mn;
#pragma unroll
      for (int j = 0; j < 16; ++j) {
        lsum[j] *= al;
        hacc[0][j] *= al;
        hacc[1][j] *= al;
      }
    }
    // exponentials (all 32 in-register)
    float e[2][16];
#pragma unroll
    for (int w = 0; w < 2; ++w)
#pragma unroll
      for (int r = 0; r < 16; ++r) e[w][r] = EXP2(sc[w][r] - m2);
    // P -> PV B-frags via cvt_pk + permlane32_swap; PV + lsum on MFMA
#pragma unroll
    for (int w = 0; w < 2; ++w)
#pragma unroll
      for (int hs = 0; hs < 2; ++hs) {
        int rb = 8 * hs;
        unsigned X0 = pk2(e[w][rb + 0], e[w][rb + 1]);
        unsigned X1 = pk2(e[w][rb + 2], e[w][rb + 3]);
        unsigned Y0 = pk2(e[w][rb + 4], e[w][rb + 5]);
        unsigned Y1 = pk2(e[w][rb + 6], e[w][rb + 7]);
        plswap2(X0, Y0);  // -> {W0, W2}
        plswap2(X1, Y1);  // -> {W1, W3}
        union { unsigned u[4]; bf16x8 v; } pB;
        pB.u[0] = X0; pB.u[1] = X1; pB.u[2] = Y0; pB.u[3] = Y1;
        int kc = 2 * w + hs;  // s-16-chunk index within the 64-s tile
        __builtin_amdgcn_s_setprio(1);
#pragma unroll
        for (int cch = 0; cch < 2; ++cch) {
          bf16x8 vA =
              *(bf16x8*)&VTl[cur][swz64(32 * cch + l32, 16 * kc + 8 * h)];
          hacc[cch] = MFMA32(vA, pB.v, hacc[cch]);
        }
        lsum = MFMA32(ones, pB.v, lsum);
        __builtin_amdgcn_s_setprio(0);
      }
  }
  float invl = 1.f / lsum[0];
  bf16* dst = hT + ((size_t)b * 1024 + tq) * 512 + hh * 64;
#pragma unroll
  for (int cch = 0; cch < 2; ++cch)
#pragma unroll
    for (int rb = 0; rb < 4; ++rb) {
      bf16x4 o4;
#pragma unroll
      for (int j = 0; j < 4; ++j) o4[j] = (bf16)(hacc[cch][4 * rb + j] * invl);
      *(bf16x4*)(dst + 32 * cch + 8 * rb + 4 * h) = o4;
    }
}

// ------------------------- proj GEMM + residual ------------------------
// 128(M) x 64(N) tile, BK=64, 2-phase double-buffered (R11-proven).
__global__ void k_proj(const bf16* __restrict__ hT, const bf16* __restrict__ wp,
                       const float* __restrict__ pb, const float* __restrict__ x,
                       float* __restrict__ out) {
  int bid = blockIdx.x;
  int swz = (bid & 7) * 64 + (bid >> 3);  // 512 blocks
  int nt = swz & 7, mt = swz >> 3;
  int tid = threadIdx.x, lane = tid & 63;
  int wid = tid >> 6, wr = wid >> 1, wc = wid & 1;
  int lr = lane & 15, lk8 = (lane >> 4) * 8, prow4 = (lane >> 4) * 4;
  __shared__ __align__(16) bf16 lA[2][8192], lB[2][4096];
  const bf16* Ab = hT + (size_t)mt * 128 * 512;
  const bf16* Bb = wp + (size_t)nt * 64 * 512;
  f32x4 acc[4][2] = {};
  int ubase = tid & 192;
  int rr8 = tid >> 3;
  int cc8 = (tid & 7) ^ (rr8 & 7);
#pragma unroll
  for (int i = 0; i < 4; ++i) {
    int r = i * 32 + rr8;
    GLOAD_LDS(Ab + (size_t)r * 512 + cc8 * 8, lA[0] + (i * 256 + ubase) * 8);
  }
#pragma unroll
  for (int i = 0; i < 2; ++i) {
    int r = i * 32 + rr8;
    GLOAD_LDS(Bb + (size_t)r * 512 + cc8 * 8, lB[0] + (i * 256 + ubase) * 8);
  }
  __syncthreads();
  for (int kt = 0; kt < 8; ++kt) {
    int cur = kt & 1;
    if (kt < 7) {
      int ktn = kt + 1;
#pragma unroll
      for (int i = 0; i < 4; ++i) {
        int r = i * 32 + rr8;
        GLOAD_LDS(Ab + (size_t)r * 512 + ktn * 64 + cc8 * 8,
                  lA[cur ^ 1] + (i * 256 + ubase) * 8);
      }
#pragma unroll
      for (int i = 0; i < 2; ++i) {
        int r = i * 32 + rr8;
        GLOAD_LDS(Bb + (size_t)r * 512 + ktn * 64 + cc8 * 8,
                  lB[cur ^ 1] + (i * 256 + ubase) * 8);
      }
    }
#pragma unroll
    for (int ksl = 0; ksl < 2; ++ksl) {
      bf16x8 aF[4], bF[2];
#pragma unroll
      for (int m = 0; m < 4; ++m)
        aF[m] = *(bf16x8*)&lA[cur][swz64(wr * 64 + m * 16 + lr, ksl * 32 + lk8)];
#pragma unroll
      for (int n = 0; n < 2; ++n)
        bF[n] = *(bf16x8*)&lB[cur][swz64(wc * 32 + n * 16 + lr, ksl * 32 + lk8)];
      __builtin_amdgcn_s_setprio(1);
#pragma unroll
      for (int m = 0; m < 4; ++m)
#pragma unroll
        for (int n = 0; n < 2; ++n) acc[m][n] = MFMA(aF[m], bF[n], acc[m][n]);
      __builtin_amdgcn_s_setprio(0);
    }
    __syncthreads();
  }
#pragma unroll
  for (int n = 0; n < 2; ++n) {
    int o = nt * 64 + wc * 32 + n * 16 + lr;
    float bias = pb[o];
#pragma unroll
    for (int m = 0; m < 4; ++m) {
      int row0 = mt * 128 + wr * 64 + m * 16 + prow4;
      int bb = row0 >> 10, t0 = row0 & 1023;
      size_t off = ((size_t)bb * 512 + o) * 1024 + t0;
      float4 xv = *(const float4*)(x + off);
      float4 rr;
      rr.x = acc[m][n][0] + xv.x + bias;
      rr.y = acc[m][n][1] + xv.y + bias;
      rr.z = acc[m][n][2] + xv.z + bias;
      rr.w = acc[m][n][3] + xv.w + bias;
      *(float4*)(out + off) = rr;
    }
  }
}

extern "C" void kernel_launch(void* const* d_in, const int* in_sizes, int n_in,
                              void* d_out, int out_size, void* d_ws, size_t ws_size,
                              hipStream_t stream) {
  const float* x = (const float*)d_in[0];
  const float* gs = (const float*)d_in[1];
  const float* gb = (const float*)d_in[2];
  const float* qw = (const float*)d_in[3];
  const float* qb = (const float*)d_in[4];
  const float* pw = (const float*)d_in[5];
  const float* pb = (const float*)d_in[6];
  float* out = (float*)d_out;
  char* ws = (char*)d_ws;
  bf16* xnT  = (bf16*)(ws);                 // 8 MB   [8192][512]
  bf16* qkvT = (bf16*)(ws + 8388608);       // 24 MB  [8192][1536] (Q,K only)
  bf16* vT   = (bf16*)(ws + 33554432);      // 8 MB   [64 heads][64 c][1024 s]
  bf16* hT   = (bf16*)(ws + 41943040);      // 8 MB   [8192][512]
  bf16* wq   = (bf16*)(ws + 50331648);      // 1.5 MB [1536][512]
  bf16* wp   = (bf16*)(ws + 51904512);      // 0.5 MB [512][512]

  k_pre<<<1280, 256, 0, stream>>>(x, gs, gb, qw, pw, xnT, wq, wp);
  k_qkv<<<768, 256, 0, stream>>>(xnT, wq, qb, qkvT, vT);
  k_attn<<<512, 256, 0, stream>>>(qkvT, vT, hT);
  k_proj<<<512, 256, 0, stream>>>(hT, wp, pb, x, out);
}

// Round 13
// 75.773 us; speedup vs baseline: 1.0241x; 1.0241x over previous
//
#include <hip/hip_runtime.h>

typedef __bf16 bf16;
typedef __attribute__((ext_vector_type(8))) __bf16 bf16x8;
typedef __attribute__((ext_vector_type(4))) __bf16 bf16x4;
typedef __attribute__((ext_vector_type(4))) float f32x4;
typedef __attribute__((ext_vector_type(2))) unsigned u32x2;

#define MFMA(a, b, c) __builtin_amdgcn_mfma_f32_16x16x32_bf16(a, b, c, 0, 0, 0)
#define GLOAD_LDS(g, l)                                                        \
  __builtin_amdgcn_global_load_lds(                                            \
      (const __attribute__((address_space(1))) void*)(g),                      \
      (__attribute__((address_space(3))) void*)(l), 16, 0, 0)

#if __has_builtin(__builtin_amdgcn_exp2f)
#define EXP2(x) __builtin_amdgcn_exp2f(x)
#else
#define EXP2(x) exp2f(x)
#endif

// 0.125 (qk scale) * log2(e): folded into K at the QKV epilogue.
#define C1LOG 0.18033688011f

// [rows][64] bf16 tile swizzle: XOR 16B-chunk index with (row&7).
__device__ __forceinline__ int swz64(int row, int col) {
  return row * 64 + (col ^ ((row & 7) << 3));
}

// pack two f32 -> u32 of 2 bf16 (lo = a)
__device__ __forceinline__ unsigned pk2(float a, float b) {
  union { __bf16 h[2]; unsigned u; } z;
  z.h[0] = (__bf16)a; z.h[1] = (__bf16)b;
  return z.u;
}

// a,b <- (a_g0,a_g1,b_g0,b_g1), (a_g2,a_g3,b_g2,b_g3)  [32-lane groups]
// semantics HW-confirmed by R12's passing 32x32 kernel
__device__ __forceinline__ void pl32(unsigned& a, unsigned& b) {
#if __has_builtin(__builtin_amdgcn_permlane32_swap)
  u32x2 r = __builtin_amdgcn_permlane32_swap(a, b, false, false);
  a = r[0]; b = r[1];
#else
  asm volatile("s_nop 1\n\tv_permlane32_swap_b32 %0, %1\n\ts_nop 1"
               : "+v"(a), "+v"(b));
#endif
}

// a,b <- (a_g0,b_g0,a_g2,b_g2), (a_g1,b_g1,a_g3,b_g3)  [16-lane groups]
__device__ __forceinline__ void pl16(unsigned& a, unsigned& b) {
#if __has_builtin(__builtin_amdgcn_permlane16_swap)
  u32x2 r = __builtin_amdgcn_permlane16_swap(a, b, false, false);
  a = r[0]; b = r[1];
#else
  asm volatile("s_nop 1\n\tv_permlane16_swap_b32 %0, %1\n\ts_nop 1"
               : "+v"(a), "+v"(b));
#endif
}

// ----------------- fused GroupNorm + weight conversion -----------------
__global__ __launch_bounds__(256, 2) void k_pre(
    const float* __restrict__ x, const float* __restrict__ gs,
    const float* __restrict__ gb, const float* __restrict__ qw,
    const float* __restrict__ pw, bf16* __restrict__ xnT,
    bf16* __restrict__ wq, bf16* __restrict__ wp) {
  int tid = threadIdx.x;
  if (blockIdx.x >= 256) {
    int i = (blockIdx.x - 256) * 256 + tid;
    int idx = i * 4;
    float4 v;
    bf16* o;
    if (idx < 786432) {
      v = *(const float4*)(qw + idx);
      o = wq + idx;
    } else {
      int j = idx - 786432;
      v = *(const float4*)(pw + j);
      o = wp + j;
    }
    o[0] = (bf16)v.x; o[1] = (bf16)v.y; o[2] = (bf16)v.z; o[3] = (bf16)v.w;
    return;
  }
  __shared__ float xs[16 * 1024];  // [ch][t], 64KB
  __shared__ float red[2][4];
  int blk = blockIdx.x;
  int b = blk >> 5, g = blk & 31;
  const float* xp = x + ((size_t)(b * 512 + g * 16)) * 1024;
  float s = 0.f, ss = 0.f;
  for (int i = tid; i < 4096; i += 256) {
    float4 v = ((const float4*)xp)[i];
    *(float4*)&xs[i * 4] = v;
    s += v.x + v.y + v.z + v.w;
    ss += v.x * v.x + v.y * v.y + v.z * v.z + v.w * v.w;
  }
#pragma unroll
  for (int m = 1; m < 64; m <<= 1) {
    s += __shfl_xor(s, m);
    ss += __shfl_xor(ss, m);
  }
  int wid = tid >> 6;
  if ((tid & 63) == 0) { red[0][wid] = s; red[1][wid] = ss; }
  __syncthreads();
  float fs = red[0][0] + red[0][1] + red[0][2] + red[0][3];
  float fss = red[1][0] + red[1][1] + red[1][2] + red[1][3];
  float mean = fs * (1.f / 16384.f);
  float var = fss * (1.f / 16384.f) - mean * mean;
  float inv = rsqrtf(var + 1e-5f);
  float a_[16], b_[16];
#pragma unroll
  for (int cl = 0; cl < 16; ++cl) {
    float sc = gs[g * 16 + cl] * inv;
    a_[cl] = sc;
    b_[cl] = gb[g * 16 + cl] - mean * sc;
  }
  int t0 = tid * 4;
  bf16 tmp[4][16];
#pragma unroll
  for (int cl = 0; cl < 16; ++cl) {
    float4 v = *(float4*)&xs[cl * 1024 + t0];
    tmp[0][cl] = (bf16)(v.x * a_[cl] + b_[cl]);
    tmp[1][cl] = (bf16)(v.y * a_[cl] + b_[cl]);
    tmp[2][cl] = (bf16)(v.z * a_[cl] + b_[cl]);
    tmp[3][cl] = (bf16)(v.w * a_[cl] + b_[cl]);
  }
  bf16* outp = xnT + (size_t)b * 1024 * 512 + g * 16;
#pragma unroll
  for (int k = 0; k < 4; ++k) {
    *(bf16x8*)(outp + (size_t)(t0 + k) * 512) = *(bf16x8*)&tmp[k][0];
    *(bf16x8*)(outp + (size_t)(t0 + k) * 512 + 8) = *(bf16x8*)&tmp[k][8];
  }
}

// ------------------------------ QKV GEMM -------------------------------
// 128x128 tile, BK=64, global_load_lds + swizzle. Epilogue: bias; K cols
// pre-scaled by 0.125*log2e; V cols written transposed into vT[head][c][s].
__global__ void k_qkv(const bf16* __restrict__ xnT, const bf16* __restrict__ wq,
                      const float* __restrict__ qb, bf16* __restrict__ qkvT,
                      bf16* __restrict__ vTout) {
  int bid = blockIdx.x;
  int swz = (bid & 7) * 96 + (bid >> 3);
  int nt = swz % 12, mt = swz / 12;
  int tid = threadIdx.x, lane = tid & 63;
  int wid = tid >> 6, wr = wid >> 1, wc = wid & 1;
  int lr = lane & 15, lk8 = (lane >> 4) * 8, prow4 = (lane >> 4) * 4;
  __shared__ __align__(16) bf16 lA[8192], lB[8192];
  const bf16* Ab = xnT + (size_t)mt * 128 * 512;
  const bf16* Bb = wq + (size_t)nt * 128 * 512;
  f32x4 acc[4][4] = {};
  int ubase = tid & 192;
  for (int kt = 0; kt < 8; ++kt) {
    __syncthreads();
#pragma unroll
    for (int i = 0; i < 4; ++i) {
      int s = i * 256 + tid;
      int r = s >> 3, cc = (s & 7) ^ (r & 7);
      GLOAD_LDS(Ab + (size_t)r * 512 + kt * 64 + cc * 8, lA + (i * 256 + ubase) * 8);
      GLOAD_LDS(Bb + (size_t)r * 512 + kt * 64 + cc * 8, lB + (i * 256 + ubase) * 8);
    }
    __syncthreads();
#pragma unroll
    for (int ksl = 0; ksl < 2; ++ksl) {
      bf16x8 aF[4], bF[4];
#pragma unroll
      for (int m = 0; m < 4; ++m)
        aF[m] = *(bf16x8*)&lA[swz64(wr * 64 + m * 16 + lr, ksl * 32 + lk8)];
#pragma unroll
      for (int n = 0; n < 4; ++n)
        bF[n] = *(bf16x8*)&lB[swz64(wc * 64 + n * 16 + lr, ksl * 32 + lk8)];
      __builtin_amdgcn_s_setprio(1);
#pragma unroll
      for (int m = 0; m < 4; ++m)
#pragma unroll
        for (int n = 0; n < 4; ++n) acc[m][n] = MFMA(aF[m], bF[n], acc[m][n]);
      __builtin_amdgcn_s_setprio(0);
    }
  }
#pragma unroll
  for (int n = 0; n < 4; ++n) {
    int o = nt * 128 + wc * 64 + n * 16 + lr;
    float bias = qb[o];
    int hh = o / 192;
    int om = o - hh * 192;
    bool isv = om >= 128;
    float scl = (om >= 64 && om < 128) ? C1LOG : 1.0f;
    int c = om - 128;
#pragma unroll
    for (int m = 0; m < 4; ++m) {
      int row0 = mt * 128 + wr * 64 + m * 16 + prow4;
      if (isv) {
        int bb = row0 >> 10, t0 = row0 & 1023;
        bf16x4 v4;
#pragma unroll
        for (int r = 0; r < 4; ++r) v4[r] = (bf16)(acc[m][n][r] + bias);
        *(bf16x4*)&vTout[(((size_t)bb * 8 + hh) * 64 + c) * 1024 + t0] = v4;
      } else {
#pragma unroll
        for (int r = 0; r < 4; ++r)
          qkvT[(size_t)(row0 + r) * 1536 + o] = (bf16)((acc[m][n][r] + bias) * scl);
      }
    }
  }
}

// --------------------------- flash attention ---------------------------
// R11 16x16 structure (16 waves/CU) + in-register P relayout: the PV
// B-frag is built from the swapped-QK^T outputs with cvt-pack + 2x
// permlane32_swap + 2x permlane16_swap per fragment (routing derived from
// the HW-confirmed swap semantics). P LDS round-trip deleted (-16KB LDS,
// -12 LDS ops and -2 lgkm drains per tile per wave).
__global__ __launch_bounds__(512, 4) void k_attn(const bf16* __restrict__ qkvT,
                                                 const bf16* __restrict__ vT,
                                                 bf16* __restrict__ hT) {
  int d = blockIdx.x;
  int head = (d & 7) * 8 + (d >> 6);  // all 8 q-tiles of a head on one XCD
  int qt = (d >> 3) & 7;
  int b = head >> 3, hh = head & 7;
  int tid = threadIdx.x, lane = tid & 63, wid = tid >> 6;
  int lr = lane & 15, hi = lane >> 4, lk8 = hi * 8;

  __shared__ __align__(16) bf16 KT[2][8192];   // [s=128][c=64] swz rows
  __shared__ __align__(16) bf16 VTl[2][8192];  // [half][c=64][s=64] swz rows

  const bf16* qbase = qkvT + (size_t)b * 1024 * 1536 + hh * 192;
  const bf16* kbase = qbase + 64;
  const bf16* vbase = vT + (size_t)head * 64 * 1024;

  int tq = qt * 128 + wid * 16 + lr;  // this lane's q row
  bf16x8 qf0 = *(const bf16x8*)(qbase + (size_t)tq * 1536 + lk8);
  bf16x8 qf1 = *(const bf16x8*)(qbase + (size_t)tq * 1536 + 32 + lk8);

  f32x4 hacc[4] = {};
  f32x4 lsum = {};
  float m2 = -1e30f;

  // staging: 1024 slots of 8 elems per 128x64 tile; thread does slots
  // {tid, tid+512} (i=0,1). row = 64*i + (tid>>3); chunk swizzle constant.
  int rr8 = tid >> 3;                       // 0..63
  int cc_ = (tid & 7) ^ (rr8 & 7);
  const bf16* ksrcT = kbase + (size_t)rr8 * 1536 + cc_ * 8;
  const bf16* vsrcT = vbase + (size_t)rr8 * 1024 + cc_ * 8;
  int ldst = wid * 512;                     // element base (i=0); +4096 (i=1)

  bf16x8 ones;
#pragma unroll
  for (int j = 0; j < 8; ++j) ones[j] = (bf16)1.0f;

  // prologue: tile 0
  GLOAD_LDS(ksrcT, KT[0] + ldst);
  GLOAD_LDS(ksrcT + (size_t)64 * 1536, KT[0] + 4096 + ldst);
  GLOAD_LDS(vsrcT, VTl[0] + ldst);
  GLOAD_LDS(vsrcT + 64, VTl[0] + 4096 + ldst);

  for (int it = 0; it < 8; ++it) {
    int cur = it & 1;
    asm volatile("s_waitcnt vmcnt(0)" ::: "memory");
    __builtin_amdgcn_s_barrier();
    __builtin_amdgcn_sched_barrier(0);
    if (it < 7) {  // prefetch next 128-row tile into the other buffer
      size_t sb = (size_t)(it + 1) * 128;
      const bf16* kp = ksrcT + sb * 1536;
      const bf16* vp = vsrcT + sb;
      GLOAD_LDS(kp, KT[cur ^ 1] + ldst);
      GLOAD_LDS(kp + (size_t)64 * 1536, KT[cur ^ 1] + 4096 + ldst);
      GLOAD_LDS(vp, VTl[cur ^ 1] + ldst);
      GLOAD_LDS(vp + 64, VTl[cur ^ 1] + 4096 + ldst);
    }
    // QK^T swapped: sc[n][r] = S[s=16n+4hi+r][q=lr]  (K pre-scaled, log2 dom)
    f32x4 sc[8];
#pragma unroll
    for (int n = 0; n < 8; ++n) sc[n] = f32x4{0.f, 0.f, 0.f, 0.f};
    __builtin_amdgcn_s_setprio(1);
#pragma unroll
    for (int n = 0; n < 8; ++n) {
      bf16x8 kA0 = *(bf16x8*)&KT[cur][swz64(n * 16 + lr, lk8)];
      bf16x8 kA1 = *(bf16x8*)&KT[cur][swz64(n * 16 + lr, 32 + lk8)];
      sc[n] = MFMA(kA0, qf0, sc[n]);
      sc[n] = MFMA(kA1, qf1, sc[n]);
    }
    __builtin_amdgcn_s_setprio(0);
    // row max over 32 regs: explicit tree (depth 5) + 2 shuffles
    float a0 = fmaxf(fmaxf(sc[0][0], sc[0][1]), fmaxf(sc[0][2], sc[0][3]));
    float a1 = fmaxf(fmaxf(sc[1][0], sc[1][1]), fmaxf(sc[1][2], sc[1][3]));
    float a2 = fmaxf(fmaxf(sc[2][0], sc[2][1]), fmaxf(sc[2][2], sc[2][3]));
    float a3 = fmaxf(fmaxf(sc[3][0], sc[3][1]), fmaxf(sc[3][2], sc[3][3]));
    float a4 = fmaxf(fmaxf(sc[4][0], sc[4][1]), fmaxf(sc[4][2], sc[4][3]));
    float a5 = fmaxf(fmaxf(sc[5][0], sc[5][1]), fmaxf(sc[5][2], sc[5][3]));
    float a6 = fmaxf(fmaxf(sc[6][0], sc[6][1]), fmaxf(sc[6][2], sc[6][3]));
    float a7 = fmaxf(fmaxf(sc[7][0], sc[7][1]), fmaxf(sc[7][2], sc[7][3]));
    float tm = fmaxf(fmaxf(fmaxf(a0, a1), fmaxf(a2, a3)),
                     fmaxf(fmaxf(a4, a5), fmaxf(a6, a7)));
    tm = fmaxf(tm, __shfl_xor(tm, 16));
    tm = fmaxf(tm, __shfl_xor(tm, 32));
    if (__any(tm > m2 + 7.213f)) {  // defer-max (5 nats, log2 domain)
      float mn = fmaxf(m2, tm);
      float al = EXP2(m2 - mn);
      m2 = mn;
      lsum[0] *= al; lsum[1] *= al; lsum[2] *= al; lsum[3] *= al;
#pragma unroll
      for (int n = 0; n < 4; ++n) {
        hacc[n][0] *= al; hacc[n][1] *= al; hacc[n][2] *= al; hacc[n][3] *= al;
      }
    }
    // PV in two s-halves; P->B-frag in registers (no LDS round-trip).
    // lane(lr,hi) holds e[n][r]=P[s=16n+4hi+r][lr]; frag word j of pa
    // must be P[s=8hi+2j,2j+1][lr]. With A=pk(e[n0][0],e[n0][1]),
    // B=pk(e[n0][2],e[n0][3]), C=pk(e[n1][0..1]), D=pk(e[n1][2..3]):
    // pl32(A,C); pl32(B,D); pl16(A,C); pl16(B,D) -> words {A,B,C,D}.
#pragma unroll
    for (int h = 0; h < 2; ++h) {
      float e[4][4];
#pragma unroll
      for (int n4 = 0; n4 < 4; ++n4) {
        int n = 4 * h + n4;
#pragma unroll
        for (int r = 0; r < 4; ++r) e[n4][r] = EXP2(sc[n][r] - m2);
      }
      unsigned A0 = pk2(e[0][0], e[0][1]), B0 = pk2(e[0][2], e[0][3]);
      unsigned C0 = pk2(e[1][0], e[1][1]), D0 = pk2(e[1][2], e[1][3]);
      unsigned A1 = pk2(e[2][0], e[2][1]), B1 = pk2(e[2][2], e[2][3]);
      unsigned C1 = pk2(e[3][0], e[3][1]), D1 = pk2(e[3][2], e[3][3]);
      pl32(A0, C0); pl32(B0, D0); pl16(A0, C0); pl16(B0, D0);
      pl32(A1, C1); pl32(B1, D1); pl16(A1, C1); pl16(B1, D1);
      union { unsigned u[4]; bf16x8 v; } pa0_, pa1_;
      pa0_.u[0] = A0; pa0_.u[1] = B0; pa0_.u[2] = C0; pa0_.u[3] = D0;
      pa1_.u[0] = A1; pa1_.u[1] = B1; pa1_.u[2] = C1; pa1_.u[3] = D1;
      const bf16* vb = VTl[cur] + h * 4096;
      __builtin_amdgcn_s_setprio(1);
#pragma unroll
      for (int n4 = 0; n4 < 4; ++n4) {
        bf16x8 vA0 = *(bf16x8*)&vb[swz64(n4 * 16 + lr, lk8)];
        bf16x8 vA1 = *(bf16x8*)&vb[swz64(n4 * 16 + lr, 32 + lk8)];
        hacc[n4] = MFMA(vA0, pa0_.v, hacc[n4]);
        hacc[n4] = MFMA(vA1, pa1_.v, hacc[n4]);
      }
      // softmax denominator on the matrix pipe: D[*][q] = sum_s P[q][s]
      lsum = MFMA(ones, pa0_.v, lsum);
      lsum = MFMA(ones, pa1_.v, lsum);
      __builtin_amdgcn_s_setprio(0);
    }
  }
  float invl = 1.f / lsum[0];
  bf16* dst = hT + ((size_t)b * 1024 + tq) * 512 + hh * 64 + hi * 4;
#pragma unroll
  for (int n = 0; n < 4; ++n) {
    bf16x4 o4;
#pragma unroll
    for (int r = 0; r < 4; ++r) o4[r] = (bf16)(hacc[n][r] * invl);
    *(bf16x4*)(dst + n * 16) = o4;
  }
}

// ------------------------- proj GEMM + residual ------------------------
// 128(M) x 64(N) tile, BK=64, 2-phase double-buffered (R11-proven).
__global__ void k_proj(const bf16* __restrict__ hT, const bf16* __restrict__ wp,
                       const float* __restrict__ pb, const float* __restrict__ x,
                       float* __restrict__ out) {
  int bid = blockIdx.x;
  int swz = (bid & 7) * 64 + (bid >> 3);  // 512 blocks
  int nt = swz & 7, mt = swz >> 3;
  int tid = threadIdx.x, lane = tid & 63;
  int wid = tid >> 6, wr = wid >> 1, wc = wid & 1;
  int lr = lane & 15, lk8 = (lane >> 4) * 8, prow4 = (lane >> 4) * 4;
  __shared__ __align__(16) bf16 lA[2][8192], lB[2][4096];
  const bf16* Ab = hT + (size_t)mt * 128 * 512;
  const bf16* Bb = wp + (size_t)nt * 64 * 512;
  f32x4 acc[4][2] = {};
  int ubase = tid & 192;
  int rr8 = tid >> 3;
  int cc8 = (tid & 7) ^ (rr8 & 7);
#pragma unroll
  for (int i = 0; i < 4; ++i) {
    int r = i * 32 + rr8;
    GLOAD_LDS(Ab + (size_t)r * 512 + cc8 * 8, lA[0] + (i * 256 + ubase) * 8);
  }
#pragma unroll
  for (int i = 0; i < 2; ++i) {
    int r = i * 32 + rr8;
    GLOAD_LDS(Bb + (size_t)r * 512 + cc8 * 8, lB[0] + (i * 256 + ubase) * 8);
  }
  __syncthreads();
  for (int kt = 0; kt < 8; ++kt) {
    int cur = kt & 1;
    if (kt < 7) {
      int ktn = kt + 1;
#pragma unroll
      for (int i = 0; i < 4; ++i) {
        int r = i * 32 + rr8;
        GLOAD_LDS(Ab + (size_t)r * 512 + ktn * 64 + cc8 * 8,
                  lA[cur ^ 1] + (i * 256 + ubase) * 8);
      }
#pragma unroll
      for (int i = 0; i < 2; ++i) {
        int r = i * 32 + rr8;
        GLOAD_LDS(Bb + (size_t)r * 512 + ktn * 64 + cc8 * 8,
                  lB[cur ^ 1] + (i * 256 + ubase) * 8);
      }
    }
#pragma unroll
    for (int ksl = 0; ksl < 2; ++ksl) {
      bf16x8 aF[4], bF[2];
#pragma unroll
      for (int m = 0; m < 4; ++m)
        aF[m] = *(bf16x8*)&lA[cur][swz64(wr * 64 + m * 16 + lr, ksl * 32 + lk8)];
#pragma unroll
      for (int n = 0; n < 2; ++n)
        bF[n] = *(bf16x8*)&lB[cur][swz64(wc * 32 + n * 16 + lr, ksl * 32 + lk8)];
      __builtin_amdgcn_s_setprio(1);
#pragma unroll
      for (int m = 0; m < 4; ++m)
#pragma unroll
        for (int n = 0; n < 2; ++n) acc[m][n] = MFMA(aF[m], bF[n], acc[m][n]);
      __builtin_amdgcn_s_setprio(0);
    }
    __syncthreads();
  }
#pragma unroll
  for (int n = 0; n < 2; ++n) {
    int o = nt * 64 + wc * 32 + n * 16 + lr;
    float bias = pb[o];
#pragma unroll
    for (int m = 0; m < 4; ++m) {
      int row0 = mt * 128 + wr * 64 + m * 16 + prow4;
      int bb = row0 >> 10, t0 = row0 & 1023;
      size_t off = ((size_t)bb * 512 + o) * 1024 + t0;
      float4 xv = *(const float4*)(x + off);
      float4 rr;
      rr.x = acc[m][n][0] + xv.x + bias;
      rr.y = acc[m][n][1] + xv.y + bias;
      rr.z = acc[m][n][2] + xv.z + bias;
      rr.w = acc[m][n][3] + xv.w + bias;
      *(float4*)(out + off) = rr;
    }
  }
}

extern "C" void kernel_launch(void* const* d_in, const int* in_sizes, int n_in,
                              void* d_out, int out_size, void* d_ws, size_t ws_size,
                              hipStream_t stream) {
  const float* x = (const float*)d_in[0];
  const float* gs = (const float*)d_in[1];
  const float* gb = (const float*)d_in[2];
  const float* qw = (const float*)d_in[3];
  const float* qb = (const float*)d_in[4];
  const float* pw = (const float*)d_in[5];
  const float* pb = (const float*)d_in[6];
  float* out = (float*)d_out;
  char* ws = (char*)d_ws;
  bf16* xnT  = (bf16*)(ws);                 // 8 MB   [8192][512]
  bf16* qkvT = (bf16*)(ws + 8388608);       // 24 MB  [8192][1536] (Q,K only)
  bf16* vT   = (bf16*)(ws + 33554432);      // 8 MB   [64 heads][64 c][1024 s]
  bf16* hT   = (bf16*)(ws + 41943040);      // 8 MB   [8192][512]
  bf16* wq   = (bf16*)(ws + 50331648);      // 1.5 MB [1536][512]
  bf16* wp   = (bf16*)(ws + 51904512);      // 0.5 MB [512][512]

  k_pre<<<1280, 256, 0, stream>>>(x, gs, gb, qw, pw, xnT, wq, wp);
  k_qkv<<<768, 256, 0, stream>>>(xnT, wq, qb, qkvT, vT);
  k_attn<<<512, 512, 0, stream>>>(qkvT, vT, hT);
  k_proj<<<512, 256, 0, stream>>>(hT, wp, pb, x, out);
}

// Round 14
// 73.324 us; speedup vs baseline: 1.0583x; 1.0334x over previous
//
#include <hip/hip_runtime.h>

typedef __bf16 bf16;
typedef __attribute__((ext_vector_type(8))) __bf16 bf16x8;
typedef __attribute__((ext_vector_type(4))) __bf16 bf16x4;
typedef __attribute__((ext_vector_type(4))) float f32x4;

#define MFMA(a, b, c) __builtin_amdgcn_mfma_f32_16x16x32_bf16(a, b, c, 0, 0, 0)
#define GLOAD_LDS(g, l)                                                        \
  __builtin_amdgcn_global_load_lds(                                            \
      (const __attribute__((address_space(1))) void*)(g),                      \
      (__attribute__((address_space(3))) void*)(l), 16, 0, 0)

#if __has_builtin(__builtin_amdgcn_exp2f)
#define EXP2(x) __builtin_amdgcn_exp2f(x)
#else
#define EXP2(x) exp2f(x)
#endif

// 0.125 (qk scale) * log2(e): folded into K at the QKV epilogue.
#define C1LOG 0.18033688011f

// [rows][64] bf16 tile swizzle: XOR 16B-chunk index with (row&7).
__device__ __forceinline__ int swz64(int row, int col) {
  return row * 64 + (col ^ ((row & 7) << 3));
}

// ----------------- fused GroupNorm + weight conversion -----------------
// blocks 0..255: GN  x[B,512,1024] f32 -> xnT [8192][512] bf16
//   single-pass: stage the 64KB group tile in LDS during the sum pass.
// blocks 256..1279: qkv_w/proj_w f32 -> bf16
__global__ __launch_bounds__(256, 2) void k_pre(
    const float* __restrict__ x, const float* __restrict__ gs,
    const float* __restrict__ gb, const float* __restrict__ qw,
    const float* __restrict__ pw, bf16* __restrict__ xnT,
    bf16* __restrict__ wq, bf16* __restrict__ wp) {
  int tid = threadIdx.x;
  if (blockIdx.x >= 256) {
    int i = (blockIdx.x - 256) * 256 + tid;
    int idx = i * 4;
    float4 v;
    bf16* o;
    if (idx < 786432) {
      v = *(const float4*)(qw + idx);
      o = wq + idx;
    } else {
      int j = idx - 786432;
      v = *(const float4*)(pw + j);
      o = wp + j;
    }
    o[0] = (bf16)v.x; o[1] = (bf16)v.y; o[2] = (bf16)v.z; o[3] = (bf16)v.w;
    return;
  }
  __shared__ float xs[16 * 1024];  // [ch][t], 64KB
  __shared__ float red[2][4];
  int blk = blockIdx.x;
  int b = blk >> 5, g = blk & 31;
  const float* xp = x + ((size_t)(b * 512 + g * 16)) * 1024;
  float s = 0.f, ss = 0.f;
  for (int i = tid; i < 4096; i += 256) {
    float4 v = ((const float4*)xp)[i];
    *(float4*)&xs[i * 4] = v;
    s += v.x + v.y + v.z + v.w;
    ss += v.x * v.x + v.y * v.y + v.z * v.z + v.w * v.w;
  }
#pragma unroll
  for (int m = 1; m < 64; m <<= 1) {
    s += __shfl_xor(s, m);
    ss += __shfl_xor(ss, m);
  }
  int wid = tid >> 6;
  if ((tid & 63) == 0) { red[0][wid] = s; red[1][wid] = ss; }
  __syncthreads();
  float fs = red[0][0] + red[0][1] + red[0][2] + red[0][3];
  float fss = red[1][0] + red[1][1] + red[1][2] + red[1][3];
  float mean = fs * (1.f / 16384.f);
  float var = fss * (1.f / 16384.f) - mean * mean;
  float inv = rsqrtf(var + 1e-5f);
  float a_[16], b_[16];
#pragma unroll
  for (int cl = 0; cl < 16; ++cl) {
    float sc = gs[g * 16 + cl] * inv;
    a_[cl] = sc;
    b_[cl] = gb[g * 16 + cl] - mean * sc;
  }
  // each thread owns 4 consecutive t; read [cl][t0..t0+3] as float4 from LDS
  int t0 = tid * 4;
  bf16 tmp[4][16];
#pragma unroll
  for (int cl = 0; cl < 16; ++cl) {
    float4 v = *(float4*)&xs[cl * 1024 + t0];
    tmp[0][cl] = (bf16)(v.x * a_[cl] + b_[cl]);
    tmp[1][cl] = (bf16)(v.y * a_[cl] + b_[cl]);
    tmp[2][cl] = (bf16)(v.z * a_[cl] + b_[cl]);
    tmp[3][cl] = (bf16)(v.w * a_[cl] + b_[cl]);
  }
  bf16* outp = xnT + (size_t)b * 1024 * 512 + g * 16;
#pragma unroll
  for (int k = 0; k < 4; ++k) {
    *(bf16x8*)(outp + (size_t)(t0 + k) * 512) = *(bf16x8*)&tmp[k][0];
    *(bf16x8*)(outp + (size_t)(t0 + k) * 512 + 8) = *(bf16x8*)&tmp[k][8];
  }
}

// ------------------------------ QKV GEMM -------------------------------
// 128x128 tile, BK=64, global_load_lds + swizzle. Epilogue: bias; K cols
// pre-scaled by 0.125*log2e; V cols written transposed into vT[head][c][s].
__global__ void k_qkv(const bf16* __restrict__ xnT, const bf16* __restrict__ wq,
                      const float* __restrict__ qb, bf16* __restrict__ qkvT,
                      bf16* __restrict__ vTout) {
  int bid = blockIdx.x;
  int swz = (bid & 7) * 96 + (bid >> 3);
  int nt = swz % 12, mt = swz / 12;
  int tid = threadIdx.x, lane = tid & 63;
  int wid = tid >> 6, wr = wid >> 1, wc = wid & 1;
  int lr = lane & 15, lk8 = (lane >> 4) * 8, prow4 = (lane >> 4) * 4;
  __shared__ __align__(16) bf16 lA[8192], lB[8192];
  const bf16* Ab = xnT + (size_t)mt * 128 * 512;
  const bf16* Bb = wq + (size_t)nt * 128 * 512;
  f32x4 acc[4][4] = {};
  int ubase = tid & 192;
  for (int kt = 0; kt < 8; ++kt) {
    __syncthreads();
#pragma unroll
    for (int i = 0; i < 4; ++i) {
      int s = i * 256 + tid;
      int r = s >> 3, cc = (s & 7) ^ (r & 7);
      GLOAD_LDS(Ab + (size_t)r * 512 + kt * 64 + cc * 8, lA + (i * 256 + ubase) * 8);
      GLOAD_LDS(Bb + (size_t)r * 512 + kt * 64 + cc * 8, lB + (i * 256 + ubase) * 8);
    }
    __syncthreads();
#pragma unroll
    for (int ksl = 0; ksl < 2; ++ksl) {
      bf16x8 aF[4], bF[4];
#pragma unroll
      for (int m = 0; m < 4; ++m)
        aF[m] = *(bf16x8*)&lA[swz64(wr * 64 + m * 16 + lr, ksl * 32 + lk8)];
#pragma unroll
      for (int n = 0; n < 4; ++n)
        bF[n] = *(bf16x8*)&lB[swz64(wc * 64 + n * 16 + lr, ksl * 32 + lk8)];
      __builtin_amdgcn_s_setprio(1);
#pragma unroll
      for (int m = 0; m < 4; ++m)
#pragma unroll
        for (int n = 0; n < 4; ++n) acc[m][n] = MFMA(aF[m], bF[n], acc[m][n]);
      __builtin_amdgcn_s_setprio(0);
    }
  }
#pragma unroll
  for (int n = 0; n < 4; ++n) {
    int o = nt * 128 + wc * 64 + n * 16 + lr;
    float bias = qb[o];
    int hh = o / 192;
    int om = o - hh * 192;
    bool isv = om >= 128;
    float scl = (om >= 64 && om < 128) ? C1LOG : 1.0f;
    int c = om - 128;
#pragma unroll
    for (int m = 0; m < 4; ++m) {
      int row0 = mt * 128 + wr * 64 + m * 16 + prow4;
      if (isv) {
        int bb = row0 >> 10, t0 = row0 & 1023;
        bf16x4 v4;
#pragma unroll
        for (int r = 0; r < 4; ++r) v4[r] = (bf16)(acc[m][n][r] + bias);
        *(bf16x4*)&vTout[(((size_t)bb * 8 + hh) * 64 + c) * 1024 + t0] = v4;
      } else {
#pragma unroll
        for (int r = 0; r < 4; ++r)
          qkvT[(size_t)(row0 + r) * 1536 + o] = (bf16)((acc[m][n][r] + bias) * scl);
      }
    }
  }
}

// --------------------------- flash attention ---------------------------
// Swapped-operand QK^T (lane owns P[s-slice][q=lr]); in-register softmax;
// KVBLK=128 double-buffered; PV in two s-halves through a 16KB per-wave
// PT; softmax denominator via MFMA(ones, P) on the matrix pipe.
// (Best-measured configuration: R6/R9/R11, 73.4-74.1 us total.)
__global__ __launch_bounds__(512, 4) void k_attn(const bf16* __restrict__ qkvT,
                                                 const bf16* __restrict__ vT,
                                                 bf16* __restrict__ hT) {
  int d = blockIdx.x;
  int head = (d & 7) * 8 + (d >> 6);  // all 8 q-tiles of a head on one XCD
  int qt = (d >> 3) & 7;
  int b = head >> 3, hh = head & 7;
  int tid = threadIdx.x, lane = tid & 63, wid = tid >> 6;
  int lr = lane & 15, hi = lane >> 4, lk8 = hi * 8;

  __shared__ __align__(16) bf16 KT[2][8192];   // [s=128][c=64] swz rows
  __shared__ __align__(16) bf16 VTl[2][8192];  // [half][c=64][s=64] swz rows
  __shared__ __align__(16) bf16 PT[8][1024];   // per-wave [q=16][s=64]

  const bf16* qbase = qkvT + (size_t)b * 1024 * 1536 + hh * 192;
  const bf16* kbase = qbase + 64;
  const bf16* vbase = vT + (size_t)head * 64 * 1024;

  int tq = qt * 128 + wid * 16 + lr;  // this lane's q row
  bf16x8 qf0 = *(const bf16x8*)(qbase + (size_t)tq * 1536 + lk8);
  bf16x8 qf1 = *(const bf16x8*)(qbase + (size_t)tq * 1536 + 32 + lk8);

  f32x4 hacc[4] = {};
  f32x4 lsum = {};
  float m2 = -1e30f;

  // staging: 1024 slots of 8 elems per 128x64 tile; thread does slots
  // {tid, tid+512} (i=0,1). row = 64*i + (tid>>3); chunk swizzle constant.
  int rr8 = tid >> 3;                       // 0..63
  int cc_ = (tid & 7) ^ (rr8 & 7);
  const bf16* ksrcT = kbase + (size_t)rr8 * 1536 + cc_ * 8;
  const bf16* vsrcT = vbase + (size_t)rr8 * 1024 + cc_ * 8;
  int ldst = wid * 512;                     // element base (i=0); +4096 (i=1)

  bf16x8 ones;
#pragma unroll
  for (int j = 0; j < 8; ++j) ones[j] = (bf16)1.0f;

  // prologue: tile 0
  GLOAD_LDS(ksrcT, KT[0] + ldst);
  GLOAD_LDS(ksrcT + (size_t)64 * 1536, KT[0] + 4096 + ldst);
  GLOAD_LDS(vsrcT, VTl[0] + ldst);
  GLOAD_LDS(vsrcT + 64, VTl[0] + 4096 + ldst);

  for (int it = 0; it < 8; ++it) {
    int cur = it & 1;
    asm volatile("s_waitcnt vmcnt(0)" ::: "memory");
    __builtin_amdgcn_s_barrier();
    __builtin_amdgcn_sched_barrier(0);
    if (it < 7) {  // prefetch next 128-row tile into the other buffer
      size_t sb = (size_t)(it + 1) * 128;
      const bf16* kp = ksrcT + sb * 1536;
      const bf16* vp = vsrcT + sb;
      GLOAD_LDS(kp, KT[cur ^ 1] + ldst);
      GLOAD_LDS(kp + (size_t)64 * 1536, KT[cur ^ 1] + 4096 + ldst);
      GLOAD_LDS(vp, VTl[cur ^ 1] + ldst);
      GLOAD_LDS(vp + 64, VTl[cur ^ 1] + 4096 + ldst);
    }
    // QK^T swapped: sc[n][r] = S[s=16n+4hi+r][q=lr]  (K pre-scaled, log2 dom)
    f32x4 sc[8];
#pragma unroll
    for (int n = 0; n < 8; ++n) sc[n] = f32x4{0.f, 0.f, 0.f, 0.f};
    __builtin_amdgcn_s_setprio(1);
#pragma unroll
    for (int n = 0; n < 8; ++n) {
      bf16x8 kA0 = *(bf16x8*)&KT[cur][swz64(n * 16 + lr, lk8)];
      bf16x8 kA1 = *(bf16x8*)&KT[cur][swz64(n * 16 + lr, 32 + lk8)];
      sc[n] = MFMA(kA0, qf0, sc[n]);
      sc[n] = MFMA(kA1, qf1, sc[n]);
    }
    __builtin_amdgcn_s_setprio(0);
    // row max over 32 regs: explicit tree (depth 5) + 2 shuffles
    float a0 = fmaxf(fmaxf(sc[0][0], sc[0][1]), fmaxf(sc[0][2], sc[0][3]));
    float a1 = fmaxf(fmaxf(sc[1][0], sc[1][1]), fmaxf(sc[1][2], sc[1][3]));
    float a2 = fmaxf(fmaxf(sc[2][0], sc[2][1]), fmaxf(sc[2][2], sc[2][3]));
    float a3 = fmaxf(fmaxf(sc[3][0], sc[3][1]), fmaxf(sc[3][2], sc[3][3]));
    float a4 = fmaxf(fmaxf(sc[4][0], sc[4][1]), fmaxf(sc[4][2], sc[4][3]));
    float a5 = fmaxf(fmaxf(sc[5][0], sc[5][1]), fmaxf(sc[5][2], sc[5][3]));
    float a6 = fmaxf(fmaxf(sc[6][0], sc[6][1]), fmaxf(sc[6][2], sc[6][3]));
    float a7 = fmaxf(fmaxf(sc[7][0], sc[7][1]), fmaxf(sc[7][2], sc[7][3]));
    float tm = fmaxf(fmaxf(fmaxf(a0, a1), fmaxf(a2, a3)),
                     fmaxf(fmaxf(a4, a5), fmaxf(a6, a7)));
    tm = fmaxf(tm, __shfl_xor(tm, 16));
    tm = fmaxf(tm, __shfl_xor(tm, 32));
    if (__any(tm > m2 + 7.213f)) {  // defer-max (5 nats, log2 domain)
      float mn = fmaxf(m2, tm);
      float al = EXP2(m2 - mn);
      m2 = mn;
      lsum[0] *= al; lsum[1] *= al; lsum[2] *= al; lsum[3] *= al;
#pragma unroll
      for (int n = 0; n < 4; ++n) {
        hacc[n][0] *= al; hacc[n][1] *= al; hacc[n][2] *= al; hacc[n][3] *= al;
      }
    }
    // PV in two s-halves through the per-wave PT tile
#pragma unroll
    for (int h = 0; h < 2; ++h) {
#pragma unroll
      for (int n4 = 0; n4 < 4; ++n4) {
        int n = 4 * h + n4;
        bf16x4 p4;
        p4[0] = (bf16)EXP2(sc[n][0] - m2);
        p4[1] = (bf16)EXP2(sc[n][1] - m2);
        p4[2] = (bf16)EXP2(sc[n][2] - m2);
        p4[3] = (bf16)EXP2(sc[n][3] - m2);
        *(bf16x4*)&PT[wid][swz64(lr, n4 * 16 + hi * 4)] = p4;  // P[q=lr][s]
      }
      // PT is wave-private: drain this wave's LDS writes only
      asm volatile("s_waitcnt lgkmcnt(0)" ::: "memory");
      __builtin_amdgcn_sched_barrier(0);
      bf16x8 pa0 = *(bf16x8*)&PT[wid][swz64(lr, lk8)];       // s_loc 8hi..
      bf16x8 pa1 = *(bf16x8*)&PT[wid][swz64(lr, 32 + lk8)];  // s_loc 32+8hi..
      const bf16* vb = VTl[cur] + h * 4096;
      __builtin_amdgcn_s_setprio(1);
#pragma unroll
      for (int n4 = 0; n4 < 4; ++n4) {
        bf16x8 vA0 = *(bf16x8*)&vb[swz64(n4 * 16 + lr, lk8)];
        bf16x8 vA1 = *(bf16x8*)&vb[swz64(n4 * 16 + lr, 32 + lk8)];
        hacc[n4] = MFMA(vA0, pa0, hacc[n4]);
        hacc[n4] = MFMA(vA1, pa1, hacc[n4]);
      }
      // softmax denominator on the matrix pipe: D[*][q] = sum_s P[q][s]
      lsum = MFMA(ones, pa0, lsum);
      lsum = MFMA(ones, pa1, lsum);
      __builtin_amdgcn_s_setprio(0);
    }
  }
  float invl = 1.f / lsum[0];
  bf16* dst = hT + ((size_t)b * 1024 + tq) * 512 + hh * 64 + hi * 4;
#pragma unroll
  for (int n = 0; n < 4; ++n) {
    bf16x4 o4;
#pragma unroll
    for (int r = 0; r < 4; ++r) o4[r] = (bf16)(hacc[n][r] * invl);
    *(bf16x4*)(dst + n * 16) = o4;
  }
}

// ------------------------- proj GEMM + residual ------------------------
// 128(M) x 64(N) tile, BK=64, 2-phase double-buffered (T3 minimum):
// stage kt+1 while computing kt, one barrier per tile. 48KB LDS keeps
// 2 blocks/CU (grid 512 all-resident). out = x + acc + pb, float4 stores.
__global__ void k_proj(const bf16* __restrict__ hT, const bf16* __restrict__ wp,
                       const float* __restrict__ pb, const float* __restrict__ x,
                       float* __restrict__ out) {
  int bid = blockIdx.x;
  int swz = (bid & 7) * 64 + (bid >> 3);  // 512 blocks
  int nt = swz & 7, mt = swz >> 3;
  int tid = threadIdx.x, lane = tid & 63;
  int wid = tid >> 6, wr = wid >> 1, wc = wid & 1;
  int lr = lane & 15, lk8 = (lane >> 4) * 8, prow4 = (lane >> 4) * 4;
  __shared__ __align__(16) bf16 lA[2][8192], lB[2][4096];
  const bf16* Ab = hT + (size_t)mt * 128 * 512;
  const bf16* Bb = wp + (size_t)nt * 64 * 512;
  f32x4 acc[4][2] = {};
  int ubase = tid & 192;
  int rr8 = tid >> 3;
  int cc8 = (tid & 7) ^ (rr8 & 7);
  // prologue: stage kt=0 into buffer 0
#pragma unroll
  for (int i = 0; i < 4; ++i) {
    int r = i * 32 + rr8;
    GLOAD_LDS(Ab + (size_t)r * 512 + cc8 * 8, lA[0] + (i * 256 + ubase) * 8);
  }
#pragma unroll
  for (int i = 0; i < 2; ++i) {
    int r = i * 32 + rr8;
    GLOAD_LDS(Bb + (size_t)r * 512 + cc8 * 8, lB[0] + (i * 256 + ubase) * 8);
  }
  __syncthreads();
  for (int kt = 0; kt < 8; ++kt) {
    int cur = kt & 1;
    if (kt < 7) {  // stage next K-slice while computing this one
      int ktn = kt + 1;
#pragma unroll
      for (int i = 0; i < 4; ++i) {
        int r = i * 32 + rr8;
        GLOAD_LDS(Ab + (size_t)r * 512 + ktn * 64 + cc8 * 8,
                  lA[cur ^ 1] + (i * 256 + ubase) * 8);
      }
#pragma unroll
      for (int i = 0; i < 2; ++i) {
        int r = i * 32 + rr8;
        GLOAD_LDS(Bb + (size_t)r * 512 + ktn * 64 + cc8 * 8,
                  lB[cur ^ 1] + (i * 256 + ubase) * 8);
      }
    }
#pragma unroll
    for (int ksl = 0; ksl < 2; ++ksl) {
      bf16x8 aF[4], bF[2];
#pragma unroll
      for (int m = 0; m < 4; ++m)
        aF[m] = *(bf16x8*)&lA[cur][swz64(wr * 64 + m * 16 + lr, ksl * 32 + lk8)];
#pragma unroll
      for (int n = 0; n < 2; ++n)
        bF[n] = *(bf16x8*)&lB[cur][swz64(wc * 32 + n * 16 + lr, ksl * 32 + lk8)];
      __builtin_amdgcn_s_setprio(1);
#pragma unroll
      for (int m = 0; m < 4; ++m)
#pragma unroll
        for (int n = 0; n < 2; ++n) acc[m][n] = MFMA(aF[m], bF[n], acc[m][n]);
      __builtin_amdgcn_s_setprio(0);
    }
    __syncthreads();  // drains vmcnt+lgkm: prefetch landed, reads done
  }
#pragma unroll
  for (int n = 0; n < 2; ++n) {
    int o = nt * 64 + wc * 32 + n * 16 + lr;
    float bias = pb[o];
#pragma unroll
    for (int m = 0; m < 4; ++m) {
      int row0 = mt * 128 + wr * 64 + m * 16 + prow4;
      int bb = row0 >> 10, t0 = row0 & 1023;
      size_t off = ((size_t)bb * 512 + o) * 1024 + t0;
      float4 xv = *(const float4*)(x + off);
      float4 rr;
      rr.x = acc[m][n][0] + xv.x + bias;
      rr.y = acc[m][n][1] + xv.y + bias;
      rr.z = acc[m][n][2] + xv.z + bias;
      rr.w = acc[m][n][3] + xv.w + bias;
      *(float4*)(out + off) = rr;
    }
  }
}

extern "C" void kernel_launch(void* const* d_in, const int* in_sizes, int n_in,
                              void* d_out, int out_size, void* d_ws, size_t ws_size,
                              hipStream_t stream) {
  const float* x = (const float*)d_in[0];
  const float* gs = (const float*)d_in[1];
  const float* gb = (const float*)d_in[2];
  const float* qw = (const float*)d_in[3];
  const float* qb = (const float*)d_in[4];
  const float* pw = (const float*)d_in[5];
  const float* pb = (const float*)d_in[6];
  float* out = (float*)d_out;
  char* ws = (char*)d_ws;
  bf16* xnT  = (bf16*)(ws);                 // 8 MB   [8192][512]
  bf16* qkvT = (bf16*)(ws + 8388608);       // 24 MB  [8192][1536] (Q,K only)
  bf16* vT   = (bf16*)(ws + 33554432);      // 8 MB   [64 heads][64 c][1024 s]
  bf16* hT   = (bf16*)(ws + 41943040);      // 8 MB   [8192][512]
  bf16* wq   = (bf16*)(ws + 50331648);      // 1.5 MB [1536][512]
  bf16* wp   = (bf16*)(ws + 51904512);      // 0.5 MB [512][512]

  k_pre<<<1280, 256, 0, stream>>>(x, gs, gb, qw, pw, xnT, wq, wp);
  k_qkv<<<768, 256, 0, stream>>>(xnT, wq, qb, qkvT, vT);
  k_attn<<<512, 512, 0, stream>>>(qkvT, vT, hT);
  k_proj<<<512, 256, 0, stream>>>(hT, wp, pb, x, out);
}